// Round 3
// baseline (321.156 us; speedup 1.0000x reference)
//
#include <hip/hip_runtime.h>
#include <hip/hip_bf16.h>
#include <cstdint>
#include <cstddef>

// Problem constants
#define B_    8
#define N_    4096
#define M_    1024
#define C1_   256
#define C2_   512
#define INCH  768     // C1+C2
#define H1    512
#define H2    256
#define ROWS  (B_*N_) // 32768
#define L1W   259     // 3+C1
#define L2W   515     // 3+C2
#define EPSV  1e-5f

typedef __bf16 bf16_t;
typedef __bf16 bf16x8 __attribute__((ext_vector_type(8)));
typedef float  f32x4  __attribute__((ext_vector_type(4)));

__device__ __forceinline__ void gload_lds16(const void* g, void* l) {
  __builtin_amdgcn_global_load_lds((const __attribute__((address_space(1))) void*)g,
                                   (__attribute__((address_space(3))) void*)l, 16, 0, 0);
}

__global__ void zero_stats_kernel(float* __restrict__ p) {
  p[blockIdx.x * 256 + threadIdx.x] = 0.f;   // grid 12 x 256 = 3072
}

// ---------------------------------------------------------------------------
// 3-NN search. Replicates reference arithmetic: d = (-2*dot + n1) + n2,
// dot = fma-chain (XLA/Eigen style), norms = sequential mul/add (no fma).
// Strict < insertion == top_k lower-index-first tie rule.
// ---------------------------------------------------------------------------
__global__ __launch_bounds__(256) void knn_kernel(const float* __restrict__ l1,
                                                  const float* __restrict__ l2,
                                                  int* __restrict__ idx_out) {
  __shared__ float sx[M_], sy[M_], sz[M_], sn[M_];
  const int b  = blockIdx.x >> 4;          // 16 blocks per batch
  const int n0 = (blockIdx.x & 15) << 8;
  const float* p2 = l2 + (size_t)b * M_ * L2W;
  for (int j = threadIdx.x; j < M_; j += 256) {
    float x = p2[(size_t)j * L2W + 0];
    float y = p2[(size_t)j * L2W + 1];
    float z = p2[(size_t)j * L2W + 2];
    sx[j] = x; sy[j] = y; sz[j] = z;
    sn[j] = __fadd_rn(__fadd_rn(__fmul_rn(x, x), __fmul_rn(y, y)), __fmul_rn(z, z));
  }
  __syncthreads();
  const int n = n0 + threadIdx.x;
  const float* p1 = l1 + ((size_t)b * N_ + n) * L1W;
  const float x = p1[0], y = p1[1], z = p1[2];
  const float nn1 = __fadd_rn(__fadd_rn(__fmul_rn(x, x), __fmul_rn(y, y)), __fmul_rn(z, z));
  float d0 = 3.4e38f, d1 = 3.4e38f, d2 = 3.4e38f;
  int   i0 = 0, i1 = 0, i2 = 0;
  for (int j = 0; j < M_; ++j) {
    float dot = __fmaf_rn(z, sz[j], __fmaf_rn(y, sy[j], __fmul_rn(x, sx[j])));
    float d   = __fadd_rn(__fadd_rn(__fmul_rn(-2.0f, dot), nn1), sn[j]);
    bool lt2 = d < d2, lt1 = d < d1, lt0 = d < d0;
    d2 = lt1 ? d1 : (lt2 ? d : d2);  i2 = lt1 ? i1 : (lt2 ? j : i2);
    d1 = lt0 ? d0 : (lt1 ? d : d1);  i1 = lt0 ? i0 : (lt1 ? j : i1);
    d0 = lt0 ? d  : d0;              i0 = lt0 ? j  : i0;
  }
  int* o = idx_out + (size_t)(b * N_ + n) * 3;
  o[0] = i0; o[1] = i1; o[2] = i2;
}

// ---------------------------------------------------------------------------
// Build X = [f1 | mean(knn feats)] as bf16 (ROWS x INCH); also copy xyz to out.
// ---------------------------------------------------------------------------
__global__ __launch_bounds__(256) void build_x_kernel(const float* __restrict__ l1,
                                                      const float* __restrict__ l2,
                                                      const int* __restrict__ idx,
                                                      bf16_t* __restrict__ X,
                                                      float* __restrict__ out) {
  const int p = blockIdx.x;      // 0..ROWS-1
  const int b = p >> 12;         // /4096
  const int t = threadIdx.x;
  const float* row1 = l1 + (size_t)p * L1W;
  if (t < 3) out[(size_t)p * L1W + t] = row1[t];
  bf16_t* xr = X + (size_t)p * INCH;
  xr[t] = (bf16_t)row1[3 + t];   // f1, t in [0,256)
  const int* ip = idx + (size_t)p * 3;
  const float* base2 = l2 + (size_t)b * M_ * L2W + 3;
  const float* r0 = base2 + (size_t)ip[0] * L2W;
  const float* r1 = base2 + (size_t)ip[1] * L2W;
  const float* r2 = base2 + (size_t)ip[2] * L2W;
  for (int c = t; c < C2_; c += 256) {
    float s = (r0[c] + r1[c] + r2[c]) * (1.0f / 3.0f);
    xr[C1_ + c] = (bf16_t)s;
  }
}

__global__ __launch_bounds__(256) void cvt_w_kernel(const float* __restrict__ W1,
                                                    const float* __restrict__ W2,
                                                    bf16_t* __restrict__ W1b,
                                                    bf16_t* __restrict__ W2b) {
  const int i = blockIdx.x * 256 + threadIdx.x;
  if (i < H1 * INCH) W1b[i] = (bf16_t)W1[i];
  if (i < H2 * H1)   W2b[i] = (bf16_t)W2[i];
}

// ---------------------------------------------------------------------------
// GEMM: Y(M x N) = A(M x K, bf16) * Bt(N x K, bf16)^T, OutT out,
// + per-column sum/sumsq partials via atomics (for global BN).
// 128x128 tile, BK=32, 4 waves, 16x16x32 MFMA.
// ---------------------------------------------------------------------------
template <typename OutT>
__global__ __launch_bounds__(256) void gemm_bn_kernel(const bf16_t* __restrict__ A,
                                                      const bf16_t* __restrict__ Bt,
                                                      OutT* __restrict__ Y,
                                                      float* __restrict__ sumv,
                                                      float* __restrict__ sqv,
                                                      const int Ncols, const int K) {
  __shared__ __align__(16) bf16_t sA[128 * 32];
  __shared__ __align__(16) bf16_t sB[128 * 32];
  const int tid  = threadIdx.x;
  const int bm   = blockIdx.x & 255;
  const int bn   = blockIdx.x >> 8;
  const int lane = tid & 63;
  const int wave = tid >> 6;
  const int wr = wave >> 1, wc = wave & 1;
  const int lr = lane & 15, lg = lane >> 4;
  const int srow = tid >> 2;          // 0..63
  const int scol = (tid & 3) * 8;     // 0,8,16,24

  const bf16_t* Ab = A  + (size_t)(bm * 128 + srow) * K + scol;
  const bf16_t* Bb = Bt + (size_t)(bn * 128 + srow) * K + scol;
  bf16_t* lA = &sA[srow * 32 + scol];  // = tid*16 bytes: lane-contiguous per wave
  bf16_t* lB = &sB[srow * 32 + scol];

  f32x4 acc[4][4];
#pragma unroll
  for (int m = 0; m < 4; ++m)
#pragma unroll
    for (int n = 0; n < 4; ++n) acc[m][n] = (f32x4){0.f, 0.f, 0.f, 0.f};

  for (int k0 = 0; k0 < K; k0 += 32) {
    gload_lds16(Ab + k0,                  lA);
    gload_lds16(Ab + (size_t)64 * K + k0, lA + 64 * 32);
    gload_lds16(Bb + k0,                  lB);
    gload_lds16(Bb + (size_t)64 * K + k0, lB + 64 * 32);
    __syncthreads();   // compiler drains vmcnt before s_barrier

    bf16x8 af[4], bq[4];
#pragma unroll
    for (int m = 0; m < 4; ++m)
      af[m] = *(const bf16x8*)&sA[(wr * 64 + m * 16 + lr) * 32 + lg * 8];
#pragma unroll
    for (int n = 0; n < 4; ++n)
      bq[n] = *(const bf16x8*)&sB[(wc * 64 + n * 16 + lr) * 32 + lg * 8];
#pragma unroll
    for (int m = 0; m < 4; ++m)
#pragma unroll
      for (int n = 0; n < 4; ++n)
        acc[m][n] = __builtin_amdgcn_mfma_f32_16x16x32_bf16(af[m], bq[n], acc[m][n], 0, 0, 0);
    __syncthreads();
  }

  // C write: row=(lane>>4)*4+reg, col=lane&15 (verified layout)
  OutT* yb = Y + (size_t)(bm * 128 + wr * 64) * Ncols + bn * 128 + wc * 64;
#pragma unroll
  for (int m = 0; m < 4; ++m) {
#pragma unroll
    for (int r = 0; r < 4; ++r) {
      const size_t ro = (size_t)(m * 16 + lg * 4 + r) * Ncols;
#pragma unroll
      for (int n = 0; n < 4; ++n)
        yb[ro + n * 16 + lr] = (OutT)acc[m][n][r];
    }
  }

  // per-column partial sums for BN stats
#pragma unroll
  for (int n = 0; n < 4; ++n) {
    float s = 0.f, q = 0.f;
#pragma unroll
    for (int m = 0; m < 4; ++m)
#pragma unroll
      for (int r = 0; r < 4; ++r) { float v = acc[m][n][r]; s += v; q += v * v; }
    s += __shfl_xor(s, 16); q += __shfl_xor(q, 16);
    s += __shfl_xor(s, 32); q += __shfl_xor(q, 32);
    if (lg == 0) {
      const int col = bn * 128 + wc * 64 + n * 16 + lr;
      atomicAdd(&sumv[col], s);
      atomicAdd(&sqv[col], q);
    }
  }
}

__global__ void bn_stats_kernel(const float* __restrict__ sum, const float* __restrict__ sq,
                                const float* __restrict__ g, const float* __restrict__ be,
                                float* __restrict__ sc, float* __restrict__ sh, int C) {
  const int c = blockIdx.x * blockDim.x + threadIdx.x;
  if (c >= C) return;
  const float invM = 1.0f / (float)ROWS;
  float mu  = sum[c] * invM;
  float var = sq[c] * invM - mu * mu;
  float rs  = rsqrtf(var + EPSV);
  float s   = rs * g[c];
  sc[c] = s;
  sh[c] = be[c] - mu * s;
}

// In-place: y(bf16) -> bf16(relu(y*sc+sh)); 8 elems/thread (C=512)
__global__ __launch_bounds__(256) void apply_bn_relu_kernel(bf16_t* __restrict__ Y,
                                                            const float* __restrict__ sc,
                                                            const float* __restrict__ sh) {
  const int i = blockIdx.x * 256 + threadIdx.x;
  const int e = i * 8;
  const int c = e & (H1 - 1);
  bf16x8 v = *(const bf16x8*)&Y[e];
  bf16x8 r;
#pragma unroll
  for (int j = 0; j < 8; ++j)
    r[j] = (bf16_t)fmaxf((float)v[j] * sc[c + j] + sh[c + j], 0.f);
  *(bf16x8*)&Y[e] = r;
}

// final: out[p][3+c] = relu(y2*sc+sh), fp32, stride-259 rows
__global__ __launch_bounds__(256) void final_kernel(const float* __restrict__ Y2,
                                                    const float* __restrict__ sc,
                                                    const float* __restrict__ sh,
                                                    float* __restrict__ out) {
  const int i = blockIdx.x * 256 + threadIdx.x;
  const int e = i * 4;
  const int p = e >> 8;         // /256
  const int c = e & 255;
  const float4 v = *(const float4*)&Y2[e];
  float* o = out + (size_t)p * L1W + 3 + c;
  o[0] = fmaxf(v.x * sc[c + 0] + sh[c + 0], 0.f);
  o[1] = fmaxf(v.y * sc[c + 1] + sh[c + 1], 0.f);
  o[2] = fmaxf(v.z * sc[c + 2] + sh[c + 2], 0.f);
  o[3] = fmaxf(v.w * sc[c + 3] + sh[c + 3], 0.f);
}

extern "C" void kernel_launch(void* const* d_in, const int* in_sizes, int n_in,
                              void* d_out, int out_size, void* d_ws, size_t ws_size,
                              hipStream_t stream) {
  const float* l1  = (const float*)d_in[0];
  const float* l2  = (const float*)d_in[1];
  const float* W1  = (const float*)d_in[2];
  const float* g1  = (const float*)d_in[4];
  const float* be1 = (const float*)d_in[5];
  const float* W2  = (const float*)d_in[6];
  const float* g2  = (const float*)d_in[8];
  const float* be2 = (const float*)d_in[9];
  float* out = (float*)d_out;
  char*  ws  = (char*)d_ws;

  // workspace layout (aliased):
  //  [0, 0.75M)      W1b (bf16)
  //  [0.75M, 1.0M)   W2b (bf16)
  //  [1.0M, +12K)    stats (3072 f32)
  //  [+12K, +384K)   idx  (ROWS*3 i32)
  //  [1.5M, +48M)    X1 (bf16, ROWS x 768)  -- later aliased by Y2 (f32, ROWS x 256)
  //  [49.5M, +32M)   Y1 (bf16, ROWS x 512)  -- BN applied in-place, becomes X2
  const size_t o_w1b   = 0;
  const size_t o_w2b   = o_w1b + (size_t)H1 * INCH * 2;      // 786432
  const size_t o_stats = o_w2b + (size_t)H2 * H1 * 2;        // 1048576
  const size_t o_idx   = o_stats + 3072 * 4;                 // 1060864
  const size_t o_X1    = 1572864;                            // 1.5 MB
  const size_t o_Y1    = o_X1 + (size_t)ROWS * INCH * 2;     // 51904512
  const size_t ws_need = o_Y1 + (size_t)ROWS * H1 * 2;       // 85458944 (~81.5 MB)

  // Defensive: if the harness workspace is smaller than required, do nothing
  // rather than fault VRAM (turns an opaque container crash into a readable
  // absmax failure that tells us ws_size is the problem).
  if (ws_size < ws_need) return;

  bf16_t* W1b = (bf16_t*)(ws + o_w1b);
  bf16_t* W2b = (bf16_t*)(ws + o_w2b);
  float* sum1 = (float*)(ws + o_stats);
  float* sq1  = sum1 + 512;
  float* sc1  = sq1 + 512;
  float* sh1  = sc1 + 512;
  float* sum2 = sh1 + 512;
  float* sq2  = sum2 + 256;
  float* sc2  = sq2 + 256;
  float* sh2  = sc2 + 256;
  int*    idxb = (int*)(ws + o_idx);
  bf16_t* X1   = (bf16_t*)(ws + o_X1);
  bf16_t* Y1   = (bf16_t*)(ws + o_Y1);   // becomes X2 in-place
  float*  Y2   = (float*)(ws + o_X1);    // aliases X1 (dead after GEMM1)

  zero_stats_kernel<<<12, 256, 0, stream>>>((float*)(ws + o_stats));
  cvt_w_kernel<<<1536, 256, 0, stream>>>(W1, W2, W1b, W2b);
  knn_kernel<<<B_ * (N_ / 256), 256, 0, stream>>>(l1, l2, idxb);
  build_x_kernel<<<ROWS, 256, 0, stream>>>(l1, l2, idxb, X1, out);
  gemm_bn_kernel<bf16_t><<<256 * (H1 / 128), 256, 0, stream>>>(X1, W1b, Y1, sum1, sq1, H1, INCH);
  bn_stats_kernel<<<2, 256, 0, stream>>>(sum1, sq1, g1, be1, sc1, sh1, H1);
  apply_bn_relu_kernel<<<(ROWS * H1 / 8) / 256, 256, 0, stream>>>(Y1, sc1, sh1);
  gemm_bn_kernel<float><<<256 * (H2 / 128), 256, 0, stream>>>(Y1, W2b, Y2, sum2, sq2, H2, H1);
  bn_stats_kernel<<<1, 256, 0, stream>>>(sum2, sq2, g2, be2, sc2, sh2, H2);
  final_kernel<<<(ROWS * H2 / 4) / 256, 256, 0, stream>>>(Y2, sc2, sh2, out);
}

// Round 5
// 304.142 us; speedup vs baseline: 1.0559x; 1.0559x over previous
//
#include <hip/hip_runtime.h>
#include <hip/hip_bf16.h>
#include <cstdint>
#include <cstddef>

// Problem constants
#define B_    8
#define N_    4096
#define M_    1024
#define C1_   256
#define C2_   512
#define INCH  768     // C1+C2
#define H1    512
#define H2    256
#define ROWS  (B_*N_) // 32768
#define L1W   259     // 3+C1
#define L2W   515     // 3+C2
#define EPSV  1e-5f

typedef __bf16 bf16_t;
typedef __bf16 bf16x8 __attribute__((ext_vector_type(8)));
typedef float  f32x4  __attribute__((ext_vector_type(4)));

__device__ __forceinline__ void gload_lds16(const void* g, void* l) {
  __builtin_amdgcn_global_load_lds((const __attribute__((address_space(1))) void*)g,
                                   (__attribute__((address_space(3))) void*)l, 16, 0, 0);
}

// ---------------------------------------------------------------------------
// cvt weights to bf16 + zero the stats region (fused; removes one launch)
// ---------------------------------------------------------------------------
__global__ __launch_bounds__(256) void cvt_w_kernel(const float* __restrict__ W1,
                                                    const float* __restrict__ W2,
                                                    bf16_t* __restrict__ W1b,
                                                    bf16_t* __restrict__ W2b,
                                                    float* __restrict__ stats) {
  const int i = blockIdx.x * 256 + threadIdx.x;
  if (i < H1 * INCH) W1b[i] = (bf16_t)W1[i];
  if (i < H2 * H1)   W2b[i] = (bf16_t)W2[i];
  if (i < 3072)      stats[i] = 0.f;
}

// ---------------------------------------------------------------------------
// 3-NN search, 4 threads per query (each scans a 256-candidate segment in
// index order with reference-exact arithmetic), then a tie-aware quad merge.
// d = (-2*dot + n1) + n2; dot = fma-chain; norms = sequential mul/add.
// Within-segment: strict < insertion (arrival order == index order).
// Cross-segment merge: strictly-less wins, exact tie -> lower index (== top_k).
// ---------------------------------------------------------------------------
__device__ __forceinline__ void insert_tie(float e, int j,
                                           float& d0, float& d1, float& d2,
                                           int& i0, int& i1, int& i2) {
  bool b2 = (e < d2) || (e == d2 && j < i2);
  bool b1 = (e < d1) || (e == d1 && j < i1);
  bool b0 = (e < d0) || (e == d0 && j < i0);
  d2 = b1 ? d1 : (b2 ? e : d2);  i2 = b1 ? i1 : (b2 ? j : i2);
  d1 = b0 ? d0 : (b1 ? e : d1);  i1 = b0 ? i0 : (b1 ? j : i1);
  d0 = b0 ? e  : d0;             i0 = b0 ? j  : i0;
}

__global__ __launch_bounds__(256) void knn_kernel(const float* __restrict__ l1,
                                                  const float* __restrict__ l2,
                                                  int* __restrict__ idx_out) {
  __shared__ float sx[M_], sy[M_], sz[M_], sn[M_];
  // 512 blocks: 64 per batch, 64 queries per block, 4 threads per query
  const int b  = blockIdx.x >> 6;
  const int q0 = (blockIdx.x & 63) << 6;
  const float* p2 = l2 + (size_t)b * M_ * L2W;
  for (int j = threadIdx.x; j < M_; j += 256) {
    float x = p2[(size_t)j * L2W + 0];
    float y = p2[(size_t)j * L2W + 1];
    float z = p2[(size_t)j * L2W + 2];
    sx[j] = x; sy[j] = y; sz[j] = z;
    sn[j] = __fadd_rn(__fadd_rn(__fmul_rn(x, x), __fmul_rn(y, y)), __fmul_rn(z, z));
  }
  __syncthreads();
  const int t   = threadIdx.x;
  const int q   = q0 + (t >> 2);
  const int seg = t & 3;
  const float* p1 = l1 + ((size_t)b * N_ + q) * L1W;
  const float x = p1[0], y = p1[1], z = p1[2];
  const float nn1 = __fadd_rn(__fadd_rn(__fmul_rn(x, x), __fmul_rn(y, y)), __fmul_rn(z, z));
  float d0 = 3.4e38f, d1 = 3.4e38f, d2 = 3.4e38f;
  int   i0 = 0, i1 = 0, i2 = 0;
  const int jbeg = seg << 8;
#pragma unroll 4
  for (int s = 0; s < 256; ++s) {
    const int j = jbeg + s;
    float dot = __fmaf_rn(z, sz[j], __fmaf_rn(y, sy[j], __fmul_rn(x, sx[j])));
    float d   = __fadd_rn(__fadd_rn(__fmul_rn(-2.0f, dot), nn1), sn[j]);
    bool lt2 = d < d2, lt1 = d < d1, lt0 = d < d0;
    d2 = lt1 ? d1 : (lt2 ? d : d2);  i2 = lt1 ? i1 : (lt2 ? j : i2);
    d1 = lt0 ? d0 : (lt1 ? d : d1);  i1 = lt0 ? i0 : (lt1 ? j : i1);
    d0 = lt0 ? d  : d0;              i0 = lt0 ? j  : i0;
  }
  // quad merge: xor 1 then xor 2; sequential tie-aware insertion of the
  // partner's ascending triple (register-only, no dynamic indexing)
#pragma unroll
  for (int m = 1; m <= 2; m <<= 1) {
    float e0 = __shfl_xor(d0, m), e1 = __shfl_xor(d1, m), e2 = __shfl_xor(d2, m);
    int   j0 = __shfl_xor(i0, m), j1 = __shfl_xor(i1, m), j2 = __shfl_xor(i2, m);
    insert_tie(e0, j0, d0, d1, d2, i0, i1, i2);
    insert_tie(e1, j1, d0, d1, d2, i0, i1, i2);
    insert_tie(e2, j2, d0, d1, d2, i0, i1, i2);
  }
  if (seg == 0) {
    int* o = idx_out + (size_t)(b * N_ + q) * 3;
    o[0] = i0; o[1] = i1; o[2] = i2;
  }
}

// ---------------------------------------------------------------------------
// Build X = [f1 | mean(knn feats)] as bf16 (ROWS x INCH); also copy xyz to out.
// 16 points per block (2048 blocks -> full occupancy, amortized setup).
// ---------------------------------------------------------------------------
__global__ __launch_bounds__(256) void build_x_kernel(const float* __restrict__ l1,
                                                      const float* __restrict__ l2,
                                                      const int* __restrict__ idx,
                                                      bf16_t* __restrict__ X,
                                                      float* __restrict__ out) {
  const int p0 = blockIdx.x * 16;
  const int t  = threadIdx.x;
  for (int pi = 0; pi < 16; ++pi) {
    const int p = p0 + pi;
    const int b = p >> 12;         // /4096
    const float* row1 = l1 + (size_t)p * L1W;
    if (t < 3) out[(size_t)p * L1W + t] = row1[t];
    bf16_t* xr = X + (size_t)p * INCH;
    xr[t] = (bf16_t)row1[3 + t];   // f1, t in [0,256)
    const int* ip = idx + (size_t)p * 3;
    const float* base2 = l2 + (size_t)b * M_ * L2W + 3;
    const float* r0 = base2 + (size_t)ip[0] * L2W;
    const float* r1 = base2 + (size_t)ip[1] * L2W;
    const float* r2 = base2 + (size_t)ip[2] * L2W;
#pragma unroll
    for (int c = t; c < C2_; c += 256) {
      float s = (r0[c] + r1[c] + r2[c]) * (1.0f / 3.0f);
      xr[C1_ + c] = (bf16_t)s;
    }
  }
}

// ---------------------------------------------------------------------------
// GEMM: Y(M x N) = A(M x K, bf16) * Bt(N x K, bf16)^T, OutT out,
// + per-column sum/sumsq partials via atomics (for global BN).
// 128x128 tile, BK=32, 4 waves, 16x16x32 MFMA. (unchanged: control group)
// ---------------------------------------------------------------------------
template <typename OutT>
__global__ __launch_bounds__(256) void gemm_bn_kernel(const bf16_t* __restrict__ A,
                                                      const bf16_t* __restrict__ Bt,
                                                      OutT* __restrict__ Y,
                                                      float* __restrict__ sumv,
                                                      float* __restrict__ sqv,
                                                      const int Ncols, const int K) {
  __shared__ __align__(16) bf16_t sA[128 * 32];
  __shared__ __align__(16) bf16_t sB[128 * 32];
  const int tid  = threadIdx.x;
  const int bm   = blockIdx.x & 255;
  const int bn   = blockIdx.x >> 8;
  const int lane = tid & 63;
  const int wave = tid >> 6;
  const int wr = wave >> 1, wc = wave & 1;
  const int lr = lane & 15, lg = lane >> 4;
  const int srow = tid >> 2;          // 0..63
  const int scol = (tid & 3) * 8;     // 0,8,16,24

  const bf16_t* Ab = A  + (size_t)(bm * 128 + srow) * K + scol;
  const bf16_t* Bb = Bt + (size_t)(bn * 128 + srow) * K + scol;
  bf16_t* lA = &sA[srow * 32 + scol];  // = tid*16 bytes: lane-contiguous per wave
  bf16_t* lB = &sB[srow * 32 + scol];

  f32x4 acc[4][4];
#pragma unroll
  for (int m = 0; m < 4; ++m)
#pragma unroll
    for (int n = 0; n < 4; ++n) acc[m][n] = (f32x4){0.f, 0.f, 0.f, 0.f};

  for (int k0 = 0; k0 < K; k0 += 32) {
    gload_lds16(Ab + k0,                  lA);
    gload_lds16(Ab + (size_t)64 * K + k0, lA + 64 * 32);
    gload_lds16(Bb + k0,                  lB);
    gload_lds16(Bb + (size_t)64 * K + k0, lB + 64 * 32);
    __syncthreads();   // compiler drains vmcnt before s_barrier

    bf16x8 af[4], bq[4];
#pragma unroll
    for (int m = 0; m < 4; ++m)
      af[m] = *(const bf16x8*)&sA[(wr * 64 + m * 16 + lr) * 32 + lg * 8];
#pragma unroll
    for (int n = 0; n < 4; ++n)
      bq[n] = *(const bf16x8*)&sB[(wc * 64 + n * 16 + lr) * 32 + lg * 8];
#pragma unroll
    for (int m = 0; m < 4; ++m)
#pragma unroll
      for (int n = 0; n < 4; ++n)
        acc[m][n] = __builtin_amdgcn_mfma_f32_16x16x32_bf16(af[m], bq[n], acc[m][n], 0, 0, 0);
    __syncthreads();
  }

  // C write: row=(lane>>4)*4+reg, col=lane&15 (verified layout)
  OutT* yb = Y + (size_t)(bm * 128 + wr * 64) * Ncols + bn * 128 + wc * 64;
#pragma unroll
  for (int m = 0; m < 4; ++m) {
#pragma unroll
    for (int r = 0; r < 4; ++r) {
      const size_t ro = (size_t)(m * 16 + lg * 4 + r) * Ncols;
#pragma unroll
      for (int n = 0; n < 4; ++n)
        yb[ro + n * 16 + lr] = (OutT)acc[m][n][r];
    }
  }

  // per-column partial sums for BN stats
#pragma unroll
  for (int n = 0; n < 4; ++n) {
    float s = 0.f, q = 0.f;
#pragma unroll
    for (int m = 0; m < 4; ++m)
#pragma unroll
      for (int r = 0; r < 4; ++r) { float v = acc[m][n][r]; s += v; q += v * v; }
    s += __shfl_xor(s, 16); q += __shfl_xor(q, 16);
    s += __shfl_xor(s, 32); q += __shfl_xor(q, 32);
    if (lg == 0) {
      const int col = bn * 128 + wc * 64 + n * 16 + lr;
      atomicAdd(&sumv[col], s);
      atomicAdd(&sqv[col], q);
    }
  }
}

__global__ void bn_stats_kernel(const float* __restrict__ sum, const float* __restrict__ sq,
                                const float* __restrict__ g, const float* __restrict__ be,
                                float* __restrict__ sc, float* __restrict__ sh, int C) {
  const int c = blockIdx.x * blockDim.x + threadIdx.x;
  if (c >= C) return;
  const float invM = 1.0f / (float)ROWS;
  float mu  = sum[c] * invM;
  float var = sq[c] * invM - mu * mu;
  float rs  = rsqrtf(var + EPSV);
  float s   = rs * g[c];
  sc[c] = s;
  sh[c] = be[c] - mu * s;
}

// In-place: y(bf16) -> bf16(relu(y*sc+sh)); 8 elems/thread (C=512)
__global__ __launch_bounds__(256) void apply_bn_relu_kernel(bf16_t* __restrict__ Y,
                                                            const float* __restrict__ sc,
                                                            const float* __restrict__ sh) {
  const int i = blockIdx.x * 256 + threadIdx.x;
  const int e = i * 8;
  const int c = e & (H1 - 1);
  bf16x8 v = *(const bf16x8*)&Y[e];
  bf16x8 r;
#pragma unroll
  for (int j = 0; j < 8; ++j)
    r[j] = (bf16_t)fmaxf((float)v[j] * sc[c + j] + sh[c + j], 0.f);
  *(bf16x8*)&Y[e] = r;
}

// final: out[p][3+c] = relu(y2*sc+sh), fp32, stride-259 rows
__global__ __launch_bounds__(256) void final_kernel(const float* __restrict__ Y2,
                                                    const float* __restrict__ sc,
                                                    const float* __restrict__ sh,
                                                    float* __restrict__ out) {
  const int i = blockIdx.x * 256 + threadIdx.x;
  const int e = i * 4;
  const int p = e >> 8;         // /256
  const int c = e & 255;
  const float4 v = *(const float4*)&Y2[e];
  float* o = out + (size_t)p * L1W + 3 + c;
  o[0] = fmaxf(v.x * sc[c + 0] + sh[c + 0], 0.f);
  o[1] = fmaxf(v.y * sc[c + 1] + sh[c + 1], 0.f);
  o[2] = fmaxf(v.z * sc[c + 2] + sh[c + 2], 0.f);
  o[3] = fmaxf(v.w * sc[c + 3] + sh[c + 3], 0.f);
}

extern "C" void kernel_launch(void* const* d_in, const int* in_sizes, int n_in,
                              void* d_out, int out_size, void* d_ws, size_t ws_size,
                              hipStream_t stream) {
  const float* l1  = (const float*)d_in[0];
  const float* l2  = (const float*)d_in[1];
  const float* W1  = (const float*)d_in[2];
  const float* g1  = (const float*)d_in[4];
  const float* be1 = (const float*)d_in[5];
  const float* W2  = (const float*)d_in[6];
  const float* g2  = (const float*)d_in[8];
  const float* be2 = (const float*)d_in[9];
  float* out = (float*)d_out;
  char*  ws  = (char*)d_ws;

  // workspace layout (aliased):
  //  [0, 0.75M)      W1b (bf16)
  //  [0.75M, 1.0M)   W2b (bf16)
  //  [1.0M, +12K)    stats (3072 f32)
  //  [+12K, +384K)   idx  (ROWS*3 i32)
  //  [1.5M, +48M)    X1 (bf16, ROWS x 768)  -- later aliased by Y2 (f32, ROWS x 256)
  //  [49.5M, +32M)   Y1 (bf16, ROWS x 512)  -- BN applied in-place, becomes X2
  const size_t o_w1b   = 0;
  const size_t o_w2b   = o_w1b + (size_t)H1 * INCH * 2;      // 786432
  const size_t o_stats = o_w2b + (size_t)H2 * H1 * 2;        // 1048576
  const size_t o_idx   = o_stats + 3072 * 4;                 // 1060864
  const size_t o_X1    = 1572864;                            // 1.5 MB
  const size_t o_Y1    = o_X1 + (size_t)ROWS * INCH * 2;     // 51904512
  const size_t ws_need = o_Y1 + (size_t)ROWS * H1 * 2;       // ~81.5 MB

  if (ws_size < ws_need) return;  // defensive: no VRAM fault on small ws

  bf16_t* W1b = (bf16_t*)(ws + o_w1b);
  bf16_t* W2b = (bf16_t*)(ws + o_w2b);
  float* sum1 = (float*)(ws + o_stats);
  float* sq1  = sum1 + 512;
  float* sc1  = sq1 + 512;
  float* sh1  = sc1 + 512;
  float* sum2 = sh1 + 512;
  float* sq2  = sum2 + 256;
  float* sc2  = sq2 + 256;
  float* sh2  = sc2 + 256;
  int*    idxb = (int*)(ws + o_idx);
  bf16_t* X1   = (bf16_t*)(ws + o_X1);
  bf16_t* Y1   = (bf16_t*)(ws + o_Y1);   // becomes X2 in-place
  float*  Y2   = (float*)(ws + o_X1);    // aliases X1 (dead after GEMM1)

  cvt_w_kernel<<<1536, 256, 0, stream>>>(W1, W2, W1b, W2b, (float*)(ws + o_stats));
  knn_kernel<<<512, 256, 0, stream>>>(l1, l2, idxb);
  build_x_kernel<<<ROWS / 16, 256, 0, stream>>>(l1, l2, idxb, X1, out);
  gemm_bn_kernel<bf16_t><<<256 * (H1 / 128), 256, 0, stream>>>(X1, W1b, Y1, sum1, sq1, H1, INCH);
  bn_stats_kernel<<<2, 256, 0, stream>>>(sum1, sq1, g1, be1, sc1, sh1, H1);
  apply_bn_relu_kernel<<<(ROWS * H1 / 8) / 256, 256, 0, stream>>>(Y1, sc1, sh1);
  gemm_bn_kernel<float><<<256 * (H2 / 128), 256, 0, stream>>>(Y1, W2b, Y2, sum2, sq2, H2, H1);
  bn_stats_kernel<<<1, 256, 0, stream>>>(sum2, sq2, g2, be2, sc2, sh2, H2);
  final_kernel<<<(ROWS * H2 / 4) / 256, 256, 0, stream>>>(Y2, sc2, sh2, out);
}

// Round 7
// 300.733 us; speedup vs baseline: 1.0679x; 1.0113x over previous
//
#include <hip/hip_runtime.h>
#include <hip/hip_bf16.h>
#include <cstdint>
#include <cstddef>

// Problem constants
#define B_    8
#define N_    4096
#define M_    1024
#define C1_   256
#define C2_   512
#define INCH  768     // C1+C2
#define H1    512
#define H2    256
#define ROWS  (B_*N_) // 32768
#define L1W   259     // 3+C1
#define L2W   515     // 3+C2
#define EPSV  1e-5f

typedef __bf16 bf16_t;
typedef __bf16 bf16x8 __attribute__((ext_vector_type(8)));
typedef float  f32x4  __attribute__((ext_vector_type(4)));

__device__ __forceinline__ void gload_lds16(const void* g, void* l) {
  __builtin_amdgcn_global_load_lds((const __attribute__((address_space(1))) void*)g,
                                   (__attribute__((address_space(3))) void*)l, 16, 0, 0);
}

// ---------------------------------------------------------------------------
// cvt weights to bf16 (stats zeroing no longer needed: no atomics)
// ---------------------------------------------------------------------------
__global__ __launch_bounds__(256) void cvt_w_kernel(const float* __restrict__ W1,
                                                    const float* __restrict__ W2,
                                                    bf16_t* __restrict__ W1b,
                                                    bf16_t* __restrict__ W2b) {
  const int i = blockIdx.x * 256 + threadIdx.x;
  if (i < H1 * INCH) W1b[i] = (bf16_t)W1[i];
  if (i < H2 * H1)   W2b[i] = (bf16_t)W2[i];
}

// ---------------------------------------------------------------------------
// 3-NN search, 4 threads per query; segments INTERLEAVED (j = 4s+seg) so the
// 4 segment-lanes read 4 consecutive LDS words (distinct banks / broadcast)
// instead of 4-way same-bank conflicts. Scan within a segment is ascending, so
// strict < keeps the lowest index; quad merge uses explicit index tie-break
// == top_k lower-index-first semantics. Reference-exact arithmetic.
// ---------------------------------------------------------------------------
__device__ __forceinline__ void insert_tie(float e, int j,
                                           float& d0, float& d1, float& d2,
                                           int& i0, int& i1, int& i2) {
  bool b2 = (e < d2) || (e == d2 && j < i2);
  bool b1 = (e < d1) || (e == d1 && j < i1);
  bool b0 = (e < d0) || (e == d0 && j < i0);
  d2 = b1 ? d1 : (b2 ? e : d2);  i2 = b1 ? i1 : (b2 ? j : i2);
  d1 = b0 ? d0 : (b1 ? e : d1);  i1 = b0 ? i0 : (b1 ? j : i1);
  d0 = b0 ? e  : d0;             i0 = b0 ? j  : i0;
}

__global__ __launch_bounds__(256) void knn_kernel(const float* __restrict__ l1,
                                                  const float* __restrict__ l2,
                                                  int* __restrict__ idx_out) {
  __shared__ float sx[M_], sy[M_], sz[M_], sn[M_];
  // 512 blocks: 64 per batch, 64 queries per block, 4 threads per query
  const int b  = blockIdx.x >> 6;
  const int q0 = (blockIdx.x & 63) << 6;
  const float* p2 = l2 + (size_t)b * M_ * L2W;
  for (int j = threadIdx.x; j < M_; j += 256) {
    float x = p2[(size_t)j * L2W + 0];
    float y = p2[(size_t)j * L2W + 1];
    float z = p2[(size_t)j * L2W + 2];
    sx[j] = x; sy[j] = y; sz[j] = z;
    sn[j] = __fadd_rn(__fadd_rn(__fmul_rn(x, x), __fmul_rn(y, y)), __fmul_rn(z, z));
  }
  __syncthreads();
  const int t   = threadIdx.x;
  const int q   = q0 + (t >> 2);
  const int seg = t & 3;
  const float* p1 = l1 + ((size_t)b * N_ + q) * L1W;
  const float x = p1[0], y = p1[1], z = p1[2];
  const float nn1 = __fadd_rn(__fadd_rn(__fmul_rn(x, x), __fmul_rn(y, y)), __fmul_rn(z, z));
  float d0 = 3.4e38f, d1 = 3.4e38f, d2 = 3.4e38f;
  int   i0 = 0, i1 = 0, i2 = 0;
#pragma unroll 4
  for (int s = 0; s < 256; ++s) {
    const int j = (s << 2) | seg;   // interleaved: ascending within segment
    float dot = __fmaf_rn(z, sz[j], __fmaf_rn(y, sy[j], __fmul_rn(x, sx[j])));
    float d   = __fadd_rn(__fadd_rn(__fmul_rn(-2.0f, dot), nn1), sn[j]);
    bool lt2 = d < d2, lt1 = d < d1, lt0 = d < d0;
    d2 = lt1 ? d1 : (lt2 ? d : d2);  i2 = lt1 ? i1 : (lt2 ? j : i2);
    d1 = lt0 ? d0 : (lt1 ? d : d1);  i1 = lt0 ? i0 : (lt1 ? j : i1);
    d0 = lt0 ? d  : d0;              i0 = lt0 ? j  : i0;
  }
  // quad merge: xor 1 then xor 2; tie-aware insertion of partner's triple
#pragma unroll
  for (int m = 1; m <= 2; m <<= 1) {
    float e0 = __shfl_xor(d0, m), e1 = __shfl_xor(d1, m), e2 = __shfl_xor(d2, m);
    int   j0 = __shfl_xor(i0, m), j1 = __shfl_xor(i1, m), j2 = __shfl_xor(i2, m);
    insert_tie(e0, j0, d0, d1, d2, i0, i1, i2);
    insert_tie(e1, j1, d0, d1, d2, i0, i1, i2);
    insert_tie(e2, j2, d0, d1, d2, i0, i1, i2);
  }
  if (seg == 0) {
    int* o = idx_out + (size_t)(b * N_ + q) * 3;
    o[0] = i0; o[1] = i1; o[2] = i2;
  }
}

// ---------------------------------------------------------------------------
// Build X = [f1 | mean(knn feats)] as bf16 (ROWS x INCH); also copy xyz to out.
// ---------------------------------------------------------------------------
__global__ __launch_bounds__(256) void build_x_kernel(const float* __restrict__ l1,
                                                      const float* __restrict__ l2,
                                                      const int* __restrict__ idx,
                                                      bf16_t* __restrict__ X,
                                                      float* __restrict__ out) {
  const int p0 = blockIdx.x * 16;
  const int t  = threadIdx.x;
  for (int pi = 0; pi < 16; ++pi) {
    const int p = p0 + pi;
    const int b = p >> 12;         // /4096
    const float* row1 = l1 + (size_t)p * L1W;
    if (t < 3) out[(size_t)p * L1W + t] = row1[t];
    bf16_t* xr = X + (size_t)p * INCH;
    xr[t] = (bf16_t)row1[3 + t];   // f1, t in [0,256)
    const int* ip = idx + (size_t)p * 3;
    const float* base2 = l2 + (size_t)b * M_ * L2W + 3;
    const float* r0 = base2 + (size_t)ip[0] * L2W;
    const float* r1 = base2 + (size_t)ip[1] * L2W;
    const float* r2 = base2 + (size_t)ip[2] * L2W;
#pragma unroll
    for (int c = t; c < C2_; c += 256) {
      float s = (r0[c] + r1[c] + r2[c]) * (1.0f / 3.0f);
      xr[C1_ + c] = (bf16_t)s;
    }
  }
}

// ---------------------------------------------------------------------------
// GEMM: Y(M x NCOLS) = A(M x K) * Bt(NCOLS x K)^T, bf16 in, OutT out.
// 128x128 tile, BK=32, 4 waves, 16x16x32 MFMA.
// Double-buffered LDS: stage tile t+1 BEFORE compute(t); ONE barrier per
// K-step (its vmcnt/lgkm drain covers the staged loads AND the consumed
// buffer -> race-free buffer swap).
// Stats: per-block column partials -> partSQ[bm][col][{s,q}] (no atomics).
// ---------------------------------------------------------------------------
template <typename OutT, int NCOLS, int KDIM>
__global__ __launch_bounds__(256) void gemm_bn_kernel(const bf16_t* __restrict__ A,
                                                      const bf16_t* __restrict__ Bt,
                                                      OutT* __restrict__ Y,
                                                      float* __restrict__ partSQ) {
  __shared__ __align__(16) bf16_t sA[2][128 * 32];
  __shared__ __align__(16) bf16_t sB[2][128 * 32];
  const int tid  = threadIdx.x;
  const int bm   = blockIdx.x & 255;
  const int bn   = blockIdx.x >> 8;
  const int lane = tid & 63;
  const int wave = tid >> 6;
  const int wr = wave >> 1, wc = wave & 1;
  const int lr = lane & 15, lg = lane >> 4;
  const int srow = tid >> 2;          // 0..63
  const int scol = (tid & 3) * 8;     // 0,8,16,24

  const bf16_t* Ab = A  + (size_t)(bm * 128 + srow) * KDIM + scol;
  const bf16_t* Bb = Bt + (size_t)(bn * 128 + srow) * KDIM + scol;
  const int loff = srow * 32 + scol;  // lds elem offset = tid*8 (16B/lane)

  f32x4 acc[4][4];
#pragma unroll
  for (int m = 0; m < 4; ++m)
#pragma unroll
    for (int n = 0; n < 4; ++n) acc[m][n] = (f32x4){0.f, 0.f, 0.f, 0.f};

  constexpr int NT = KDIM / 32;   // even (24 or 16)

#define STAGE(BUF, T)                                                   \
  do {                                                                  \
    const int k0_ = (T) * 32;                                           \
    gload_lds16(Ab + k0_,                      &sA[BUF][loff]);         \
    gload_lds16(Ab + (size_t)64 * KDIM + k0_,  &sA[BUF][loff + 64*32]); \
    gload_lds16(Bb + k0_,                      &sB[BUF][loff]);         \
    gload_lds16(Bb + (size_t)64 * KDIM + k0_,  &sB[BUF][loff + 64*32]); \
  } while (0)

#define COMPUTE(BUF)                                                          \
  do {                                                                        \
    bf16x8 af[4], bq[4];                                                      \
    _Pragma("unroll")                                                         \
    for (int m = 0; m < 4; ++m)                                               \
      af[m] = *(const bf16x8*)&sA[BUF][(wr * 64 + m * 16 + lr) * 32 + lg * 8];\
    _Pragma("unroll")                                                         \
    for (int n = 0; n < 4; ++n)                                               \
      bq[n] = *(const bf16x8*)&sB[BUF][(wc * 64 + n * 16 + lr) * 32 + lg * 8];\
    _Pragma("unroll")                                                         \
    for (int m = 0; m < 4; ++m)                                               \
      _Pragma("unroll")                                                       \
      for (int n = 0; n < 4; ++n)                                             \
        acc[m][n] = __builtin_amdgcn_mfma_f32_16x16x32_bf16(af[m], bq[n],     \
                                                            acc[m][n], 0, 0, 0);\
  } while (0)

  STAGE(0, 0);
  __syncthreads();
  for (int t = 0; t < NT; t += 2) {
    STAGE(1, t + 1);                 // overlap with compute(0)
    COMPUTE(0);
    __syncthreads();                 // drains stage(1) + protects buf0
    if (t + 2 < NT) STAGE(0, t + 2); // overlap with compute(1)
    COMPUTE(1);
    __syncthreads();                 // drains stage(0) + protects buf1
  }
#undef STAGE
#undef COMPUTE

  // C write: row=(lane>>4)*4+reg, col=lane&15 (verified layout)
  OutT* yb = Y + (size_t)(bm * 128 + wr * 64) * NCOLS + bn * 128 + wc * 64;
#pragma unroll
  for (int m = 0; m < 4; ++m) {
#pragma unroll
    for (int r = 0; r < 4; ++r) {
      const size_t ro = (size_t)(m * 16 + lg * 4 + r) * NCOLS;
#pragma unroll
      for (int n = 0; n < 4; ++n)
        yb[ro + n * 16 + lr] = (OutT)acc[m][n][r];
    }
  }

  // per-block column partials (no atomics): reduce over lg via shfl, then
  // over wr via LDS (sA is free after the last barrier above).
  float* red = (float*)&sA[0][0];   // 512 floats used
#pragma unroll
  for (int n = 0; n < 4; ++n) {
    float s = 0.f, q = 0.f;
#pragma unroll
    for (int m = 0; m < 4; ++m)
#pragma unroll
      for (int r = 0; r < 4; ++r) { float v = acc[m][n][r]; s += v; q += v * v; }
    s += __shfl_xor(s, 16); q += __shfl_xor(q, 16);
    s += __shfl_xor(s, 32); q += __shfl_xor(q, 32);
    if (lg == 0) {
      const int base = (((wc * 4 + n) * 16 + lr) * 2 + wr) * 2;
      red[base + 0] = s;
      red[base + 1] = q;
    }
  }
  __syncthreads();
  if (tid < 128) {
    const int wc_ = tid >> 6, n_ = (tid >> 4) & 3, lr_ = tid & 15;
    const int b0 = (((wc_ * 4 + n_) * 16 + lr_) * 2 + 0) * 2;
    const int b1 = (((wc_ * 4 + n_) * 16 + lr_) * 2 + 1) * 2;
    const int col = bn * 128 + wc_ * 64 + n_ * 16 + lr_;
    float* dst = partSQ + ((size_t)bm * NCOLS + col) * 2;
    dst[0] = red[b0] + red[b1];
    dst[1] = red[b0 + 1] + red[b1 + 1];
  }
}

// reduce 256 bm-partials per column -> BN scale/shift
__global__ void bn_stats_kernel(const float* __restrict__ partSQ,
                                const float* __restrict__ g, const float* __restrict__ be,
                                float* __restrict__ sc, float* __restrict__ sh, int C) {
  const int c = blockIdx.x * blockDim.x + threadIdx.x;
  if (c >= C) return;
  float s = 0.f, q = 0.f;
  for (int bm = 0; bm < 256; ++bm) {
    s += partSQ[((size_t)bm * C + c) * 2 + 0];
    q += partSQ[((size_t)bm * C + c) * 2 + 1];
  }
  const float invM = 1.0f / (float)ROWS;
  float mu  = s * invM;
  float var = q * invM - mu * mu;
  float rs  = rsqrtf(var + EPSV);
  float sv  = rs * g[c];
  sc[c] = sv;
  sh[c] = be[c] - mu * sv;
}

// In-place: y(bf16) -> bf16(relu(y*sc+sh)); 8 elems/thread (C=512)
__global__ __launch_bounds__(256) void apply_bn_relu_kernel(bf16_t* __restrict__ Y,
                                                            const float* __restrict__ sc,
                                                            const float* __restrict__ sh) {
  const int i = blockIdx.x * 256 + threadIdx.x;
  const int e = i * 8;
  const int c = e & (H1 - 1);
  bf16x8 v = *(const bf16x8*)&Y[e];
  bf16x8 r;
#pragma unroll
  for (int j = 0; j < 8; ++j)
    r[j] = (bf16_t)fmaxf((float)v[j] * sc[c + j] + sh[c + j], 0.f);
  *(bf16x8*)&Y[e] = r;
}

// final: out[p][3+c] = relu(y2*sc+sh), fp32, stride-259 rows
__global__ __launch_bounds__(256) void final_kernel(const float* __restrict__ Y2,
                                                    const float* __restrict__ sc,
                                                    const float* __restrict__ sh,
                                                    float* __restrict__ out) {
  const int i = blockIdx.x * 256 + threadIdx.x;
  const int e = i * 4;
  const int p = e >> 8;         // /256
  const int c = e & 255;
  const float4 v = *(const float4*)&Y2[e];
  float* o = out + (size_t)p * L1W + 3 + c;
  o[0] = fmaxf(v.x * sc[c + 0] + sh[c + 0], 0.f);
  o[1] = fmaxf(v.y * sc[c + 1] + sh[c + 1], 0.f);
  o[2] = fmaxf(v.z * sc[c + 2] + sh[c + 2], 0.f);
  o[3] = fmaxf(v.w * sc[c + 3] + sh[c + 3], 0.f);
}

extern "C" void kernel_launch(void* const* d_in, const int* in_sizes, int n_in,
                              void* d_out, int out_size, void* d_ws, size_t ws_size,
                              hipStream_t stream) {
  const float* l1  = (const float*)d_in[0];
  const float* l2  = (const float*)d_in[1];
  const float* W1  = (const float*)d_in[2];
  const float* g1  = (const float*)d_in[4];
  const float* be1 = (const float*)d_in[5];
  const float* W2  = (const float*)d_in[6];
  const float* g2  = (const float*)d_in[8];
  const float* be2 = (const float*)d_in[9];
  float* out = (float*)d_out;
  char*  ws  = (char*)d_ws;

  // workspace layout (aliased, ~82.5 MB):
  const size_t o_w1b  = 0;                                   // 786432
  const size_t o_w2b  = o_w1b + (size_t)H1 * INCH * 2;       // +262144 -> 1048576
  const size_t o_sc   = 1048576;                             // 1536 f32 -> 6144
  const size_t o_idx  = 1054720;                             // ROWS*3*4 = 393216
  const size_t o_part = 1447936;                             // 256*512*2*4 = 1048576
  const size_t o_X1   = 2621440;                             // ROWS*768*2 = 50331648
  const size_t o_Y1   = o_X1 + (size_t)ROWS * INCH * 2;      // 52953088
  const size_t ws_need = o_Y1 + (size_t)ROWS * H1 * 2;       // 86507520

  if (ws_size < ws_need) return;  // defensive: no VRAM fault on small ws

  bf16_t* W1b = (bf16_t*)(ws + o_w1b);
  bf16_t* W2b = (bf16_t*)(ws + o_w2b);
  float* sc1  = (float*)(ws + o_sc);
  float* sh1  = sc1 + 512;
  float* sc2  = sh1 + 512;
  float* sh2  = sc2 + 256;
  int*    idxb = (int*)(ws + o_idx);
  float* partSQ = (float*)(ws + o_part);
  bf16_t* X1   = (bf16_t*)(ws + o_X1);
  bf16_t* Y1   = (bf16_t*)(ws + o_Y1);   // becomes X2 in-place
  float*  Y2   = (float*)(ws + o_X1);    // aliases X1 (dead after GEMM1)

  cvt_w_kernel<<<1536, 256, 0, stream>>>(W1, W2, W1b, W2b);
  knn_kernel<<<512, 256, 0, stream>>>(l1, l2, idxb);
  build_x_kernel<<<ROWS / 16, 256, 0, stream>>>(l1, l2, idxb, X1, out);
  gemm_bn_kernel<bf16_t, H1, INCH><<<256 * (H1 / 128), 256, 0, stream>>>(X1, W1b, Y1, partSQ);
  bn_stats_kernel<<<2, 256, 0, stream>>>(partSQ, g1, be1, sc1, sh1, H1);
  apply_bn_relu_kernel<<<(ROWS * H1 / 8) / 256, 256, 0, stream>>>(Y1, sc1, sh1);
  gemm_bn_kernel<float, H2, H1><<<256 * (H2 / 128), 256, 0, stream>>>(Y1, W2b, Y2, partSQ);
  bn_stats_kernel<<<1, 256, 0, stream>>>(partSQ, g2, be2, sc2, sh2, H2);
  final_kernel<<<(ROWS * H2 / 4) / 256, 256, 0, stream>>>(Y2, sc2, sh2, out);
}

// Round 9
// 253.623 us; speedup vs baseline: 1.2663x; 1.1857x over previous
//
#include <hip/hip_runtime.h>
#include <hip/hip_bf16.h>
#include <cstdint>
#include <cstddef>

// Problem constants
#define B_    8
#define N_    4096
#define M_    1024
#define C1_   256
#define C2_   512
#define INCH  768     // C1+C2
#define H1    512
#define H2    256
#define ROWS  (B_*N_) // 32768
#define L1W   259     // 3+C1
#define L2W   515     // 3+C2
#define EPSV  1e-5f

typedef __bf16 bf16_t;
typedef __bf16 bf16x2 __attribute__((ext_vector_type(2)));
typedef __bf16 bf16x8 __attribute__((ext_vector_type(8)));
typedef float  f32x4  __attribute__((ext_vector_type(4)));

__device__ __forceinline__ void gload_lds16(const void* g, void* l) {
  __builtin_amdgcn_global_load_lds((const __attribute__((address_space(1))) void*)g,
                                   (__attribute__((address_space(3))) void*)l, 16, 0, 0);
}

// ---------------------------------------------------------------------------
// cvt weights to bf16 + convert f2 (layer2 features) to compact bf16 [b][m][512]
// grid 16384 x 256 = 4,194,304 threads = f2 element count; coalesced.
// ---------------------------------------------------------------------------
__global__ __launch_bounds__(256) void cvt_w_kernel(const float* __restrict__ W1,
                                                    const float* __restrict__ W2,
                                                    const float* __restrict__ l2,
                                                    bf16_t* __restrict__ W1b,
                                                    bf16_t* __restrict__ W2b,
                                                    bf16_t* __restrict__ f2b) {
  const int i = blockIdx.x * 256 + threadIdx.x;
  if (i < H1 * INCH) W1b[i] = (bf16_t)W1[i];
  if (i < H2 * H1)   W2b[i] = (bf16_t)W2[i];
  const int row = i >> 9, c = i & 511;      // i < 4194304 always
  f2b[i] = (bf16_t)l2[(size_t)row * L2W + 3 + c];
}

// ---------------------------------------------------------------------------
// 3-NN search, 4 threads per query; segments interleaved (j = 4s+seg).
// Reference-exact arithmetic; tie-aware merge == top_k semantics.
// ---------------------------------------------------------------------------
__device__ __forceinline__ void insert_tie(float e, int j,
                                           float& d0, float& d1, float& d2,
                                           int& i0, int& i1, int& i2) {
  bool b2 = (e < d2) || (e == d2 && j < i2);
  bool b1 = (e < d1) || (e == d1 && j < i1);
  bool b0 = (e < d0) || (e == d0 && j < i0);
  d2 = b1 ? d1 : (b2 ? e : d2);  i2 = b1 ? i1 : (b2 ? j : i2);
  d1 = b0 ? d0 : (b1 ? e : d1);  i1 = b0 ? i0 : (b1 ? j : i1);
  d0 = b0 ? e  : d0;             i0 = b0 ? j  : i0;
}

__global__ __launch_bounds__(256) void knn_kernel(const float* __restrict__ l1,
                                                  const float* __restrict__ l2,
                                                  int* __restrict__ idx_out) {
  __shared__ float sx[M_], sy[M_], sz[M_], sn[M_];
  const int b  = blockIdx.x >> 6;
  const int q0 = (blockIdx.x & 63) << 6;
  const float* p2 = l2 + (size_t)b * M_ * L2W;
  for (int j = threadIdx.x; j < M_; j += 256) {
    float x = p2[(size_t)j * L2W + 0];
    float y = p2[(size_t)j * L2W + 1];
    float z = p2[(size_t)j * L2W + 2];
    sx[j] = x; sy[j] = y; sz[j] = z;
    sn[j] = __fadd_rn(__fadd_rn(__fmul_rn(x, x), __fmul_rn(y, y)), __fmul_rn(z, z));
  }
  __syncthreads();
  const int t   = threadIdx.x;
  const int q   = q0 + (t >> 2);
  const int seg = t & 3;
  const float* p1 = l1 + ((size_t)b * N_ + q) * L1W;
  const float x = p1[0], y = p1[1], z = p1[2];
  const float nn1 = __fadd_rn(__fadd_rn(__fmul_rn(x, x), __fmul_rn(y, y)), __fmul_rn(z, z));
  float d0 = 3.4e38f, d1 = 3.4e38f, d2 = 3.4e38f;
  int   i0 = 0, i1 = 0, i2 = 0;
#pragma unroll 4
  for (int s = 0; s < 256; ++s) {
    const int j = (s << 2) | seg;
    float dot = __fmaf_rn(z, sz[j], __fmaf_rn(y, sy[j], __fmul_rn(x, sx[j])));
    float d   = __fadd_rn(__fadd_rn(__fmul_rn(-2.0f, dot), nn1), sn[j]);
    bool lt2 = d < d2, lt1 = d < d1, lt0 = d < d0;
    d2 = lt1 ? d1 : (lt2 ? d : d2);  i2 = lt1 ? i1 : (lt2 ? j : i2);
    d1 = lt0 ? d0 : (lt1 ? d : d1);  i1 = lt0 ? i0 : (lt1 ? j : i1);
    d0 = lt0 ? d  : d0;              i0 = lt0 ? j  : i0;
  }
#pragma unroll
  for (int m = 1; m <= 2; m <<= 1) {
    float e0 = __shfl_xor(d0, m), e1 = __shfl_xor(d1, m), e2 = __shfl_xor(d2, m);
    int   j0 = __shfl_xor(i0, m), j1 = __shfl_xor(i1, m), j2 = __shfl_xor(i2, m);
    insert_tie(e0, j0, d0, d1, d2, i0, i1, i2);
    insert_tie(e1, j1, d0, d1, d2, i0, i1, i2);
    insert_tie(e2, j2, d0, d1, d2, i0, i1, i2);
  }
  if (seg == 0) {
    int* o = idx_out + (size_t)(b * N_ + q) * 3;
    o[0] = i0; o[1] = i1; o[2] = i2;
  }
}

// ---------------------------------------------------------------------------
// Build X = [f1 | mean(knn feats)] as bf16; gathers from compact bf16 f2b
// (half the gather traffic vs fp32). 2 channels/thread, 4B vector loads.
// ---------------------------------------------------------------------------
__global__ __launch_bounds__(256) void build_x_kernel(const float* __restrict__ l1,
                                                      const bf16_t* __restrict__ f2b,
                                                      const int* __restrict__ idx,
                                                      bf16_t* __restrict__ X,
                                                      float* __restrict__ out) {
  const int p0 = blockIdx.x * 16;
  const int t  = threadIdx.x;
  const int c  = t * 2;
  for (int pi = 0; pi < 16; ++pi) {
    const int p = p0 + pi;
    const int b = p >> 12;         // /4096
    const float* row1 = l1 + (size_t)p * L1W;
    if (t < 3) out[(size_t)p * L1W + t] = row1[t];
    bf16_t* xr = X + (size_t)p * INCH;
    xr[t] = (bf16_t)row1[3 + t];   // f1, t in [0,256)
    const int* ip = idx + (size_t)p * 3;
    const bf16_t* base2 = f2b + (size_t)b * M_ * C2_;
    const bf16_t* r0 = base2 + (size_t)ip[0] * C2_;
    const bf16_t* r1 = base2 + (size_t)ip[1] * C2_;
    const bf16_t* r2 = base2 + (size_t)ip[2] * C2_;
    bf16x2 v0 = *(const bf16x2*)&r0[c];
    bf16x2 v1 = *(const bf16x2*)&r1[c];
    bf16x2 v2 = *(const bf16x2*)&r2[c];
    bf16x2 w;
    w[0] = (bf16_t)(((float)v0[0] + (float)v1[0] + (float)v2[0]) * (1.0f / 3.0f));
    w[1] = (bf16_t)(((float)v0[1] + (float)v1[1] + (float)v2[1]) * (1.0f / 3.0f));
    *(bf16x2*)&xr[C1_ + c] = w;
  }
}

// ---------------------------------------------------------------------------
// GEMM: Y(M x NCOLS) = A(M x K) * Bt(NCOLS x K)^T, bf16 in, OutT out.
// 128x128 tile, BK=32, 4 waves, double-buffered LDS (stage t+1 before
// compute t, one barrier per K-step). partSQ[bm][col][{s,q}], no atomics.
// (UNCHANGED from round 5: control group)
// ---------------------------------------------------------------------------
template <typename OutT, int NCOLS, int KDIM>
__global__ __launch_bounds__(256) void gemm_bn_kernel(const bf16_t* __restrict__ A,
                                                      const bf16_t* __restrict__ Bt,
                                                      OutT* __restrict__ Y,
                                                      float* __restrict__ partSQ) {
  __shared__ __align__(16) bf16_t sA[2][128 * 32];
  __shared__ __align__(16) bf16_t sB[2][128 * 32];
  const int tid  = threadIdx.x;
  const int bm   = blockIdx.x & 255;
  const int bn   = blockIdx.x >> 8;
  const int lane = tid & 63;
  const int wave = tid >> 6;
  const int wr = wave >> 1, wc = wave & 1;
  const int lr = lane & 15, lg = lane >> 4;
  const int srow = tid >> 2;          // 0..63
  const int scol = (tid & 3) * 8;     // 0,8,16,24

  const bf16_t* Ab = A  + (size_t)(bm * 128 + srow) * KDIM + scol;
  const bf16_t* Bb = Bt + (size_t)(bn * 128 + srow) * KDIM + scol;
  const int loff = srow * 32 + scol;  // lds elem offset = tid*8 (16B/lane)

  f32x4 acc[4][4];
#pragma unroll
  for (int m = 0; m < 4; ++m)
#pragma unroll
    for (int n = 0; n < 4; ++n) acc[m][n] = (f32x4){0.f, 0.f, 0.f, 0.f};

  constexpr int NT = KDIM / 32;   // even (24 or 16)

#define STAGE(BUF, T)                                                   \
  do {                                                                  \
    const int k0_ = (T) * 32;                                           \
    gload_lds16(Ab + k0_,                      &sA[BUF][loff]);         \
    gload_lds16(Ab + (size_t)64 * KDIM + k0_,  &sA[BUF][loff + 64*32]); \
    gload_lds16(Bb + k0_,                      &sB[BUF][loff]);         \
    gload_lds16(Bb + (size_t)64 * KDIM + k0_,  &sB[BUF][loff + 64*32]); \
  } while (0)

#define COMPUTE(BUF)                                                          \
  do {                                                                        \
    bf16x8 af[4], bq[4];                                                      \
    _Pragma("unroll")                                                         \
    for (int m = 0; m < 4; ++m)                                               \
      af[m] = *(const bf16x8*)&sA[BUF][(wr * 64 + m * 16 + lr) * 32 + lg * 8];\
    _Pragma("unroll")                                                         \
    for (int n = 0; n < 4; ++n)                                               \
      bq[n] = *(const bf16x8*)&sB[BUF][(wc * 64 + n * 16 + lr) * 32 + lg * 8];\
    _Pragma("unroll")                                                         \
    for (int m = 0; m < 4; ++m)                                               \
      _Pragma("unroll")                                                       \
      for (int n = 0; n < 4; ++n)                                             \
        acc[m][n] = __builtin_amdgcn_mfma_f32_16x16x32_bf16(af[m], bq[n],     \
                                                            acc[m][n], 0, 0, 0);\
  } while (0)

  STAGE(0, 0);
  __syncthreads();
  for (int t = 0; t < NT; t += 2) {
    STAGE(1, t + 1);                 // overlap with compute(0)
    COMPUTE(0);
    __syncthreads();                 // drains stage(1) + protects buf0
    if (t + 2 < NT) STAGE(0, t + 2); // overlap with compute(1)
    COMPUTE(1);
    __syncthreads();                 // drains stage(0) + protects buf1
  }
#undef STAGE
#undef COMPUTE

  // C write: row=(lane>>4)*4+reg, col=lane&15 (verified layout)
  OutT* yb = Y + (size_t)(bm * 128 + wr * 64) * NCOLS + bn * 128 + wc * 64;
#pragma unroll
  for (int m = 0; m < 4; ++m) {
#pragma unroll
    for (int r = 0; r < 4; ++r) {
      const size_t ro = (size_t)(m * 16 + lg * 4 + r) * NCOLS;
#pragma unroll
      for (int n = 0; n < 4; ++n)
        yb[ro + n * 16 + lr] = (OutT)acc[m][n][r];
    }
  }

  // per-block column partials (no atomics)
  float* red = (float*)&sA[0][0];   // 512 floats used
#pragma unroll
  for (int n = 0; n < 4; ++n) {
    float s = 0.f, q = 0.f;
#pragma unroll
    for (int m = 0; m < 4; ++m)
#pragma unroll
      for (int r = 0; r < 4; ++r) { float v = acc[m][n][r]; s += v; q += v * v; }
    s += __shfl_xor(s, 16); q += __shfl_xor(q, 16);
    s += __shfl_xor(s, 32); q += __shfl_xor(q, 32);
    if (lg == 0) {
      const int base = (((wc * 4 + n) * 16 + lr) * 2 + wr) * 2;
      red[base + 0] = s;
      red[base + 1] = q;
    }
  }
  __syncthreads();
  if (tid < 128) {
    const int wc_ = tid >> 6, n_ = (tid >> 4) & 3, lr_ = tid & 15;
    const int b0 = (((wc_ * 4 + n_) * 16 + lr_) * 2 + 0) * 2;
    const int b1 = (((wc_ * 4 + n_) * 16 + lr_) * 2 + 1) * 2;
    const int col = bn * 128 + wc_ * 64 + n_ * 16 + lr_;
    float* dst = partSQ + ((size_t)bm * NCOLS + col) * 2;
    dst[0] = red[b0] + red[b1];
    dst[1] = red[b0 + 1] + red[b1 + 1];
  }
}

// ---------------------------------------------------------------------------
// reduce 256 bm-partials per column -> BN scale/shift.
// One block PER CHANNEL (Guideline 1: 512/256 blocks, not 2); thread t owns
// partial bm=t (float2), shfl+LDS reduce.
// ---------------------------------------------------------------------------
template <int C>
__global__ __launch_bounds__(256) void bn_stats_kernel(const float* __restrict__ partSQ,
                                                       const float* __restrict__ g,
                                                       const float* __restrict__ be,
                                                       float* __restrict__ sc,
                                                       float* __restrict__ sh) {
  __shared__ float red[8];
  const int c = blockIdx.x;
  const int t = threadIdx.x;
  const float2 v = *(const float2*)&partSQ[((size_t)t * C + c) * 2];
  float s = v.x, q = v.y;
#pragma unroll
  for (int m = 32; m >= 1; m >>= 1) { s += __shfl_xor(s, m); q += __shfl_xor(q, m); }
  if ((t & 63) == 0) { red[(t >> 6) * 2] = s; red[(t >> 6) * 2 + 1] = q; }
  __syncthreads();
  if (t == 0) {
    s = red[0] + red[2] + red[4] + red[6];
    q = red[1] + red[3] + red[5] + red[7];
    const float invM = 1.0f / (float)ROWS;
    float mu  = s * invM;
    float var = q * invM - mu * mu;
    float rs  = rsqrtf(var + EPSV);
    float sv  = rs * g[c];
    sc[c] = sv;
    sh[c] = be[c] - mu * sv;
  }
}

// In-place: y(bf16) -> bf16(relu(y*sc+sh)); 8 elems/thread (C=512)
__global__ __launch_bounds__(256) void apply_bn_relu_kernel(bf16_t* __restrict__ Y,
                                                            const float* __restrict__ sc,
                                                            const float* __restrict__ sh) {
  const int i = blockIdx.x * 256 + threadIdx.x;
  const int e = i * 8;
  const int c = e & (H1 - 1);
  bf16x8 v = *(const bf16x8*)&Y[e];
  bf16x8 r;
#pragma unroll
  for (int j = 0; j < 8; ++j)
    r[j] = (bf16_t)fmaxf((float)v[j] * sc[c + j] + sh[c + j], 0.f);
  *(bf16x8*)&Y[e] = r;
}

// final: out[p][3+c] = relu(y2*sc+sh), fp32, stride-259 rows
__global__ __launch_bounds__(256) void final_kernel(const float* __restrict__ Y2,
                                                    const float* __restrict__ sc,
                                                    const float* __restrict__ sh,
                                                    float* __restrict__ out) {
  const int i = blockIdx.x * 256 + threadIdx.x;
  const int e = i * 4;
  const int p = e >> 8;         // /256
  const int c = e & 255;
  const float4 v = *(const float4*)&Y2[e];
  float* o = out + (size_t)p * L1W + 3 + c;
  o[0] = fmaxf(v.x * sc[c + 0] + sh[c + 0], 0.f);
  o[1] = fmaxf(v.y * sc[c + 1] + sh[c + 1], 0.f);
  o[2] = fmaxf(v.z * sc[c + 2] + sh[c + 2], 0.f);
  o[3] = fmaxf(v.w * sc[c + 3] + sh[c + 3], 0.f);
}

extern "C" void kernel_launch(void* const* d_in, const int* in_sizes, int n_in,
                              void* d_out, int out_size, void* d_ws, size_t ws_size,
                              hipStream_t stream) {
  const float* l1  = (const float*)d_in[0];
  const float* l2  = (const float*)d_in[1];
  const float* W1  = (const float*)d_in[2];
  const float* g1  = (const float*)d_in[4];
  const float* be1 = (const float*)d_in[5];
  const float* W2  = (const float*)d_in[6];
  const float* g2  = (const float*)d_in[8];
  const float* be2 = (const float*)d_in[9];
  float* out = (float*)d_out;
  char*  ws  = (char*)d_ws;

  // workspace layout (aliased, ~82.5 MB — same as round 5, known-good):
  const size_t o_w1b  = 0;                                   // 786432
  const size_t o_w2b  = o_w1b + (size_t)H1 * INCH * 2;       // -> 1048576
  const size_t o_sc   = 1048576;                             // 6144
  const size_t o_idx  = 1054720;                             // 393216
  const size_t o_part = 1447936;                             // 1048576
  const size_t o_X1   = 2621440;                             // 50331648
  const size_t o_Y1   = o_X1 + (size_t)ROWS * INCH * 2;      // 52953088
  const size_t ws_need = o_Y1 + (size_t)ROWS * H1 * 2;       // 86507520

  if (ws_size < ws_need) return;  // defensive: no VRAM fault on small ws

  bf16_t* W1b = (bf16_t*)(ws + o_w1b);
  bf16_t* W2b = (bf16_t*)(ws + o_w2b);
  float* sc1  = (float*)(ws + o_sc);
  float* sh1  = sc1 + 512;
  float* sc2  = sh1 + 512;
  float* sh2  = sc2 + 256;
  int*    idxb = (int*)(ws + o_idx);
  float* partSQ = (float*)(ws + o_part);
  bf16_t* X1   = (bf16_t*)(ws + o_X1);
  bf16_t* Y1   = (bf16_t*)(ws + o_Y1);   // becomes X2 in-place
  float*  Y2   = (float*)(ws + o_X1);    // aliases X1 (dead after GEMM1)
  bf16_t* f2b  = (bf16_t*)(ws + o_Y1);   // aliases Y1: f2b dead before GEMM1 writes Y1

  cvt_w_kernel<<<16384, 256, 0, stream>>>(W1, W2, l2, W1b, W2b, f2b);
  knn_kernel<<<512, 256, 0, stream>>>(l1, l2, idxb);
  build_x_kernel<<<ROWS / 16, 256, 0, stream>>>(l1, f2b, idxb, X1, out);
  gemm_bn_kernel<bf16_t, H1, INCH><<<256 * (H1 / 128), 256, 0, stream>>>(X1, W1b, Y1, partSQ);
  bn_stats_kernel<H1><<<H1, 256, 0, stream>>>(partSQ, g1, be1, sc1, sh1);
  apply_bn_relu_kernel<<<(ROWS * H1 / 8) / 256, 256, 0, stream>>>(Y1, sc1, sh1);
  gemm_bn_kernel<float, H2, H1><<<256 * (H2 / 128), 256, 0, stream>>>(Y1, W2b, Y2, partSQ);
  bn_stats_kernel<H2><<<H2, 256, 0, stream>>>(partSQ, g2, be2, sc2, sh2);
  final_kernel<<<(ROWS * H2 / 4) / 256, 256, 0, stream>>>(Y2, sc2, sh2, out);
}

// Round 10
// 245.725 us; speedup vs baseline: 1.3070x; 1.0321x over previous
//
#include <hip/hip_runtime.h>
#include <hip/hip_bf16.h>
#include <cstdint>
#include <cstddef>

// Problem constants
#define B_    8
#define N_    4096
#define M_    1024
#define C1_   256
#define C2_   512
#define INCH  768     // C1+C2
#define H1    512
#define H2    256
#define ROWS  (B_*N_) // 32768
#define L1W   259     // 3+C1
#define L2W   515     // 3+C2
#define EPSV  1e-5f

typedef __bf16 bf16_t;
typedef __bf16 bf16x2 __attribute__((ext_vector_type(2)));
typedef __bf16 bf16x8 __attribute__((ext_vector_type(8)));
typedef float  f32x4  __attribute__((ext_vector_type(4)));

__device__ __forceinline__ void gload_lds16(const void* g, void* l) {
  __builtin_amdgcn_global_load_lds((const __attribute__((address_space(1))) void*)g,
                                   (__attribute__((address_space(3))) void*)l, 16, 0, 0);
}

// ---------------------------------------------------------------------------
// cvt weights to bf16 + convert f2 (layer2 features) to compact bf16 [b][m][512]
// ---------------------------------------------------------------------------
__global__ __launch_bounds__(256) void cvt_w_kernel(const float* __restrict__ W1,
                                                    const float* __restrict__ W2,
                                                    const float* __restrict__ l2,
                                                    bf16_t* __restrict__ W1b,
                                                    bf16_t* __restrict__ W2b,
                                                    bf16_t* __restrict__ f2b) {
  const int i = blockIdx.x * 256 + threadIdx.x;
  if (i < H1 * INCH) W1b[i] = (bf16_t)W1[i];
  if (i < H2 * H1)   W2b[i] = (bf16_t)W2[i];
  const int row = i >> 9, c = i & 511;      // i < 4194304 always
  f2b[i] = (bf16_t)l2[(size_t)row * L2W + 3 + c];
}

// ---------------------------------------------------------------------------
// 3-NN search, 4 threads per query; segments interleaved (j = 4s+seg).
// Reference-exact arithmetic; tie-aware merge == top_k semantics.
// ---------------------------------------------------------------------------
__device__ __forceinline__ void insert_tie(float e, int j,
                                           float& d0, float& d1, float& d2,
                                           int& i0, int& i1, int& i2) {
  bool b2 = (e < d2) || (e == d2 && j < i2);
  bool b1 = (e < d1) || (e == d1 && j < i1);
  bool b0 = (e < d0) || (e == d0 && j < i0);
  d2 = b1 ? d1 : (b2 ? e : d2);  i2 = b1 ? i1 : (b2 ? j : i2);
  d1 = b0 ? d0 : (b1 ? e : d1);  i1 = b0 ? i0 : (b1 ? j : i1);
  d0 = b0 ? e  : d0;             i0 = b0 ? j  : i0;
}

__global__ __launch_bounds__(256) void knn_kernel(const float* __restrict__ l1,
                                                  const float* __restrict__ l2,
                                                  int* __restrict__ idx_out) {
  __shared__ float sx[M_], sy[M_], sz[M_], sn[M_];
  const int b  = blockIdx.x >> 6;
  const int q0 = (blockIdx.x & 63) << 6;
  const float* p2 = l2 + (size_t)b * M_ * L2W;
  for (int j = threadIdx.x; j < M_; j += 256) {
    float x = p2[(size_t)j * L2W + 0];
    float y = p2[(size_t)j * L2W + 1];
    float z = p2[(size_t)j * L2W + 2];
    sx[j] = x; sy[j] = y; sz[j] = z;
    sn[j] = __fadd_rn(__fadd_rn(__fmul_rn(x, x), __fmul_rn(y, y)), __fmul_rn(z, z));
  }
  __syncthreads();
  const int t   = threadIdx.x;
  const int q   = q0 + (t >> 2);
  const int seg = t & 3;
  const float* p1 = l1 + ((size_t)b * N_ + q) * L1W;
  const float x = p1[0], y = p1[1], z = p1[2];
  const float nn1 = __fadd_rn(__fadd_rn(__fmul_rn(x, x), __fmul_rn(y, y)), __fmul_rn(z, z));
  float d0 = 3.4e38f, d1 = 3.4e38f, d2 = 3.4e38f;
  int   i0 = 0, i1 = 0, i2 = 0;
#pragma unroll 4
  for (int s = 0; s < 256; ++s) {
    const int j = (s << 2) | seg;
    float dot = __fmaf_rn(z, sz[j], __fmaf_rn(y, sy[j], __fmul_rn(x, sx[j])));
    float d   = __fadd_rn(__fadd_rn(__fmul_rn(-2.0f, dot), nn1), sn[j]);
    bool lt2 = d < d2, lt1 = d < d1, lt0 = d < d0;
    d2 = lt1 ? d1 : (lt2 ? d : d2);  i2 = lt1 ? i1 : (lt2 ? j : i2);
    d1 = lt0 ? d0 : (lt1 ? d : d1);  i1 = lt0 ? i0 : (lt1 ? j : i1);
    d0 = lt0 ? d  : d0;              i0 = lt0 ? j  : i0;
  }
#pragma unroll
  for (int m = 1; m <= 2; m <<= 1) {
    float e0 = __shfl_xor(d0, m), e1 = __shfl_xor(d1, m), e2 = __shfl_xor(d2, m);
    int   j0 = __shfl_xor(i0, m), j1 = __shfl_xor(i1, m), j2 = __shfl_xor(i2, m);
    insert_tie(e0, j0, d0, d1, d2, i0, i1, i2);
    insert_tie(e1, j1, d0, d1, d2, i0, i1, i2);
    insert_tie(e2, j2, d0, d1, d2, i0, i1, i2);
  }
  if (seg == 0) {
    int* o = idx_out + (size_t)(b * N_ + q) * 3;
    o[0] = i0; o[1] = i1; o[2] = i2;
  }
}

// ---------------------------------------------------------------------------
// Build X = [f1 | mean(knn feats)] as bf16; gathers from compact bf16 f2b.
// ---------------------------------------------------------------------------
__global__ __launch_bounds__(256) void build_x_kernel(const float* __restrict__ l1,
                                                      const bf16_t* __restrict__ f2b,
                                                      const int* __restrict__ idx,
                                                      bf16_t* __restrict__ X,
                                                      float* __restrict__ out) {
  const int p0 = blockIdx.x * 16;
  const int t  = threadIdx.x;
  const int c  = t * 2;
  for (int pi = 0; pi < 16; ++pi) {
    const int p = p0 + pi;
    const int b = p >> 12;         // /4096
    const float* row1 = l1 + (size_t)p * L1W;
    if (t < 3) out[(size_t)p * L1W + t] = row1[t];
    bf16_t* xr = X + (size_t)p * INCH;
    xr[t] = (bf16_t)row1[3 + t];   // f1, t in [0,256)
    const int* ip = idx + (size_t)p * 3;
    const bf16_t* base2 = f2b + (size_t)b * M_ * C2_;
    const bf16_t* r0 = base2 + (size_t)ip[0] * C2_;
    const bf16_t* r1 = base2 + (size_t)ip[1] * C2_;
    const bf16_t* r2 = base2 + (size_t)ip[2] * C2_;
    bf16x2 v0 = *(const bf16x2*)&r0[c];
    bf16x2 v1 = *(const bf16x2*)&r1[c];
    bf16x2 v2 = *(const bf16x2*)&r2[c];
    bf16x2 w;
    w[0] = (bf16_t)(((float)v0[0] + (float)v1[0] + (float)v2[0]) * (1.0f / 3.0f));
    w[1] = (bf16_t)(((float)v0[1] + (float)v1[1] + (float)v2[1]) * (1.0f / 3.0f));
    *(bf16x2*)&xr[C1_ + c] = w;
  }
}

// ---------------------------------------------------------------------------
// GEMM: Y(M x NCOLS) = A(M x K) * Bt(NCOLS x K)^T, bf16 in, OutT out.
// 128x128 tile, BK=32, 4 waves, double-buffered LDS (stage t+1 before
// compute t, one barrier per K-step). partSQ[bm][col][{s,q}], no atomics.
// FUSE: apply per-k-channel BN+ReLU (x = relu(x*sc[k]+sh[k])) to the
// A-fragments after ds_read (k = KB + lg*8 + j) -- replaces the standalone
// apply_bn_relu kernel for layer 2. Identical numerics (same double
// bf16 quantization as the two-kernel path).
// ---------------------------------------------------------------------------
template <typename OutT, int NCOLS, int KDIM, bool FUSE>
__global__ __launch_bounds__(256) void gemm_bn_kernel(const bf16_t* __restrict__ A,
                                                      const bf16_t* __restrict__ Bt,
                                                      OutT* __restrict__ Y,
                                                      float* __restrict__ partSQ,
                                                      const float* __restrict__ scp,
                                                      const float* __restrict__ shp) {
  __shared__ __align__(16) bf16_t sA[2][128 * 32];
  __shared__ __align__(16) bf16_t sB[2][128 * 32];
  __shared__ __align__(16) float smSC[FUSE ? KDIM : 4];
  __shared__ __align__(16) float smSH[FUSE ? KDIM : 4];
  const int tid  = threadIdx.x;
  const int bm   = blockIdx.x & 255;
  const int bn   = blockIdx.x >> 8;
  const int lane = tid & 63;
  const int wave = tid >> 6;
  const int wr = wave >> 1, wc = wave & 1;
  const int lr = lane & 15, lg = lane >> 4;
  const int srow = tid >> 2;          // 0..63
  const int scol = (tid & 3) * 8;     // 0,8,16,24

  const bf16_t* Ab = A  + (size_t)(bm * 128 + srow) * KDIM + scol;
  const bf16_t* Bb = Bt + (size_t)(bn * 128 + srow) * KDIM + scol;
  const int loff = srow * 32 + scol;  // lds elem offset = tid*8 (16B/lane)

  if constexpr (FUSE) {
    for (int i = tid; i < KDIM; i += 256) { smSC[i] = scp[i]; smSH[i] = shp[i]; }
  }

  f32x4 acc[4][4];
#pragma unroll
  for (int m = 0; m < 4; ++m)
#pragma unroll
    for (int n = 0; n < 4; ++n) acc[m][n] = (f32x4){0.f, 0.f, 0.f, 0.f};

  constexpr int NT = KDIM / 32;   // even (24 or 16)

#define STAGE(BUF, T)                                                   \
  do {                                                                  \
    const int k0_ = (T) * 32;                                           \
    gload_lds16(Ab + k0_,                      &sA[BUF][loff]);         \
    gload_lds16(Ab + (size_t)64 * KDIM + k0_,  &sA[BUF][loff + 64*32]); \
    gload_lds16(Bb + k0_,                      &sB[BUF][loff]);         \
    gload_lds16(Bb + (size_t)64 * KDIM + k0_,  &sB[BUF][loff + 64*32]); \
  } while (0)

#define COMPUTE(BUF, KB)                                                      \
  do {                                                                        \
    bf16x8 af[4], bq[4];                                                      \
    _Pragma("unroll")                                                         \
    for (int m = 0; m < 4; ++m)                                               \
      af[m] = *(const bf16x8*)&sA[BUF][(wr * 64 + m * 16 + lr) * 32 + lg * 8];\
    _Pragma("unroll")                                                         \
    for (int n = 0; n < 4; ++n)                                               \
      bq[n] = *(const bf16x8*)&sB[BUF][(wc * 64 + n * 16 + lr) * 32 + lg * 8];\
    if constexpr (FUSE) {                                                     \
      const f32x4 s0 = *(const f32x4*)&smSC[(KB) + lg * 8];                   \
      const f32x4 s1 = *(const f32x4*)&smSC[(KB) + lg * 8 + 4];               \
      const f32x4 h0 = *(const f32x4*)&smSH[(KB) + lg * 8];                   \
      const f32x4 h1 = *(const f32x4*)&smSH[(KB) + lg * 8 + 4];               \
      _Pragma("unroll")                                                       \
      for (int m = 0; m < 4; ++m) {                                           \
        _Pragma("unroll")                                                     \
        for (int j = 0; j < 4; ++j) {                                         \
          af[m][j]     = (bf16_t)fmaxf((float)af[m][j]     * s0[j] + h0[j], 0.f); \
          af[m][j + 4] = (bf16_t)fmaxf((float)af[m][j + 4] * s1[j] + h1[j], 0.f); \
        }                                                                     \
      }                                                                       \
    }                                                                         \
    _Pragma("unroll")                                                         \
    for (int m = 0; m < 4; ++m)                                               \
      _Pragma("unroll")                                                       \
      for (int n = 0; n < 4; ++n)                                             \
        acc[m][n] = __builtin_amdgcn_mfma_f32_16x16x32_bf16(af[m], bq[n],     \
                                                            acc[m][n], 0, 0, 0);\
  } while (0)

  STAGE(0, 0);
  __syncthreads();                     // also covers smSC/smSH ds_writes
  for (int t = 0; t < NT; t += 2) {
    STAGE(1, t + 1);                 // overlap with compute(0)
    COMPUTE(0, t * 32);
    __syncthreads();                 // drains stage(1) + protects buf0
    if (t + 2 < NT) STAGE(0, t + 2); // overlap with compute(1)
    COMPUTE(1, (t + 1) * 32);
    __syncthreads();                 // drains stage(0) + protects buf1
  }
#undef STAGE
#undef COMPUTE

  // C write: row=(lane>>4)*4+reg, col=lane&15 (verified layout)
  OutT* yb = Y + (size_t)(bm * 128 + wr * 64) * NCOLS + bn * 128 + wc * 64;
#pragma unroll
  for (int m = 0; m < 4; ++m) {
#pragma unroll
    for (int r = 0; r < 4; ++r) {
      const size_t ro = (size_t)(m * 16 + lg * 4 + r) * NCOLS;
#pragma unroll
      for (int n = 0; n < 4; ++n)
        yb[ro + n * 16 + lr] = (OutT)acc[m][n][r];
    }
  }

  // per-block column partials (no atomics)
  float* red = (float*)&sA[0][0];   // 512 floats used
#pragma unroll
  for (int n = 0; n < 4; ++n) {
    float s = 0.f, q = 0.f;
#pragma unroll
    for (int m = 0; m < 4; ++m)
#pragma unroll
      for (int r = 0; r < 4; ++r) { float v = acc[m][n][r]; s += v; q += v * v; }
    s += __shfl_xor(s, 16); q += __shfl_xor(q, 16);
    s += __shfl_xor(s, 32); q += __shfl_xor(q, 32);
    if (lg == 0) {
      const int base = (((wc * 4 + n) * 16 + lr) * 2 + wr) * 2;
      red[base + 0] = s;
      red[base + 1] = q;
    }
  }
  __syncthreads();
  if (tid < 128) {
    const int wc_ = tid >> 6, n_ = (tid >> 4) & 3, lr_ = tid & 15;
    const int b0 = (((wc_ * 4 + n_) * 16 + lr_) * 2 + 0) * 2;
    const int b1 = (((wc_ * 4 + n_) * 16 + lr_) * 2 + 1) * 2;
    const int col = bn * 128 + wc_ * 64 + n_ * 16 + lr_;
    float* dst = partSQ + ((size_t)bm * NCOLS + col) * 2;
    dst[0] = red[b0] + red[b1];
    dst[1] = red[b0 + 1] + red[b1 + 1];
  }
}

// ---------------------------------------------------------------------------
// reduce 256 bm-partials per column -> BN scale/shift. One block per channel.
// ---------------------------------------------------------------------------
template <int C>
__global__ __launch_bounds__(256) void bn_stats_kernel(const float* __restrict__ partSQ,
                                                       const float* __restrict__ g,
                                                       const float* __restrict__ be,
                                                       float* __restrict__ sc,
                                                       float* __restrict__ sh) {
  __shared__ float red[8];
  const int c = blockIdx.x;
  const int t = threadIdx.x;
  const float2 v = *(const float2*)&partSQ[((size_t)t * C + c) * 2];
  float s = v.x, q = v.y;
#pragma unroll
  for (int m = 32; m >= 1; m >>= 1) { s += __shfl_xor(s, m); q += __shfl_xor(q, m); }
  if ((t & 63) == 0) { red[(t >> 6) * 2] = s; red[(t >> 6) * 2 + 1] = q; }
  __syncthreads();
  if (t == 0) {
    s = red[0] + red[2] + red[4] + red[6];
    q = red[1] + red[3] + red[5] + red[7];
    const float invM = 1.0f / (float)ROWS;
    float mu  = s * invM;
    float var = q * invM - mu * mu;
    float rs  = rsqrtf(var + EPSV);
    float sv  = rs * g[c];
    sc[c] = sv;
    sh[c] = be[c] - mu * sv;
  }
}

// final: out[p][3+c] = relu(y2*sc+sh), fp32, stride-259 rows
__global__ __launch_bounds__(256) void final_kernel(const float* __restrict__ Y2,
                                                    const float* __restrict__ sc,
                                                    const float* __restrict__ sh,
                                                    float* __restrict__ out) {
  const int i = blockIdx.x * 256 + threadIdx.x;
  const int e = i * 4;
  const int p = e >> 8;         // /256
  const int c = e & 255;
  const float4 v = *(const float4*)&Y2[e];
  float* o = out + (size_t)p * L1W + 3 + c;
  o[0] = fmaxf(v.x * sc[c + 0] + sh[c + 0], 0.f);
  o[1] = fmaxf(v.y * sc[c + 1] + sh[c + 1], 0.f);
  o[2] = fmaxf(v.z * sc[c + 2] + sh[c + 2], 0.f);
  o[3] = fmaxf(v.w * sc[c + 3] + sh[c + 3], 0.f);
}

extern "C" void kernel_launch(void* const* d_in, const int* in_sizes, int n_in,
                              void* d_out, int out_size, void* d_ws, size_t ws_size,
                              hipStream_t stream) {
  const float* l1  = (const float*)d_in[0];
  const float* l2  = (const float*)d_in[1];
  const float* W1  = (const float*)d_in[2];
  const float* g1  = (const float*)d_in[4];
  const float* be1 = (const float*)d_in[5];
  const float* W2  = (const float*)d_in[6];
  const float* g2  = (const float*)d_in[8];
  const float* be2 = (const float*)d_in[9];
  float* out = (float*)d_out;
  char*  ws  = (char*)d_ws;

  // workspace layout (aliased, ~82.5 MB — known-good):
  const size_t o_w1b  = 0;                                   // 786432
  const size_t o_w2b  = o_w1b + (size_t)H1 * INCH * 2;       // -> 1048576
  const size_t o_sc   = 1048576;                             // 6144
  const size_t o_idx  = 1054720;                             // 393216
  const size_t o_part = 1447936;                             // 1048576
  const size_t o_X1   = 2621440;                             // 50331648
  const size_t o_Y1   = o_X1 + (size_t)ROWS * INCH * 2;      // 52953088
  const size_t ws_need = o_Y1 + (size_t)ROWS * H1 * 2;       // 86507520

  if (ws_size < ws_need) return;  // defensive: no VRAM fault on small ws

  bf16_t* W1b = (bf16_t*)(ws + o_w1b);
  bf16_t* W2b = (bf16_t*)(ws + o_w2b);
  float* sc1  = (float*)(ws + o_sc);
  float* sh1  = sc1 + 512;
  float* sc2  = sh1 + 512;
  float* sh2  = sc2 + 256;
  int*    idxb = (int*)(ws + o_idx);
  float* partSQ = (float*)(ws + o_part);
  bf16_t* X1   = (bf16_t*)(ws + o_X1);
  bf16_t* Y1   = (bf16_t*)(ws + o_Y1);   // raw pre-BN; GEMM2 fuses BN+ReLU
  float*  Y2   = (float*)(ws + o_X1);    // aliases X1 (dead after GEMM1)
  bf16_t* f2b  = (bf16_t*)(ws + o_Y1);   // aliases Y1: f2b dead before GEMM1 writes Y1

  cvt_w_kernel<<<16384, 256, 0, stream>>>(W1, W2, l2, W1b, W2b, f2b);
  knn_kernel<<<512, 256, 0, stream>>>(l1, l2, idxb);
  build_x_kernel<<<ROWS / 16, 256, 0, stream>>>(l1, f2b, idxb, X1, out);
  gemm_bn_kernel<bf16_t, H1, INCH, false><<<256 * (H1 / 128), 256, 0, stream>>>(
      X1, W1b, Y1, partSQ, nullptr, nullptr);
  bn_stats_kernel<H1><<<H1, 256, 0, stream>>>(partSQ, g1, be1, sc1, sh1);
  gemm_bn_kernel<float, H2, H1, true><<<256 * (H2 / 128), 256, 0, stream>>>(
      Y1, W2b, Y2, partSQ, sc1, sh1);
  bn_stats_kernel<H2><<<H2, 256, 0, stream>>>(partSQ, g2, be2, sc2, sh2);
  final_kernel<<<(ROWS * H2 / 4) / 256, 256, 0, stream>>>(Y2, sc2, sh2, out);
}